// Round 17
// baseline (56.848 us; speedup 1.0000x reference)
//
#include <hip/hip_runtime.h>
#include <hip/hip_bf16.h>

// FAVOR+ bidirectional linear attention, N=262144, D=64, fp32 in/out.
// R16 champion (53.9us) + pass2 at TRUE 4 blocks/CU: GRID2 1024, TPB2 4,
// (256,2) bounds (128 VGPR x 4 waves/SIMD = exact fit; LDS 17.4KB x 4 fits).
// Pass 1 (512 blocks, (256,4)): K/V projections (bf16 MFMA) -> kv via
//   LDS-transpose MFMA accumulate -> per-block partial kv/ksum; block 0
//   zero-inits kvFin/ksFin; first x-tile loads hoisted above staging.
// Reduce (20 blocks): coalesced slice sums -> atomicAdd into kvFin/ksFin.
// Pass 2 (1024 blocks, (256,2), zero LDS/barriers in loop): swapped Q-proj
//   qp^T = mfma(Wq, x); out^T = mfma(kvA_pi, qp_repack); denom = per-lane
//   dot + 2 shfl_xor; float4 stores; x loads hoisted above staging.

#define NPTS 262144
#define TILES (NPTS / 64)      // 4096
#define GRID1 512
#define TPB1 (TILES / GRID1)   // 8
#define GRID2 1024
#define TPB2 (TILES / GRID2)   // 4
#define EPS 1e-3f

typedef __attribute__((ext_vector_type(8))) short short8;   // 8 x bf16 (4 VGPRs)
typedef __attribute__((ext_vector_type(4))) float f32x4;

__device__ __forceinline__ unsigned short f2bf(float f) {
    unsigned u = __builtin_bit_cast(unsigned, f);
    u += 0x7FFFu + ((u >> 16) & 1u);           // round-to-nearest-even
    return (unsigned short)(u >> 16);
}

__device__ __forceinline__ short8 cvt8(float4 p0, float4 p1) {
    short8 a;
    a[0] = (short)f2bf(p0.x); a[1] = (short)f2bf(p0.y); a[2] = (short)f2bf(p0.z); a[3] = (short)f2bf(p0.w);
    a[4] = (short)f2bf(p1.x); a[5] = (short)f2bf(p1.y); a[6] = (short)f2bf(p1.z); a[7] = (short)f2bf(p1.w);
    return a;
}

// barrier that drains LDS ops only (keeps global prefetch loads in flight)
__device__ __forceinline__ void lds_barrier() {
    asm volatile("s_waitcnt lgkmcnt(0)" ::: "memory");
    __builtin_amdgcn_s_barrier();
}

// coalesced stage of a 64x64 f32 matrix -> LDS bf16 [64][72]
__device__ __forceinline__ void stage_mat(const float* __restrict__ W,
                                          unsigned short (*dst)[72], int srow, int sc0) {
    const float* p = W + srow * 64 + sc0;
    float4 f0 = ((const float4*)p)[0];
    float4 f1 = ((const float4*)p)[1];
    float4 f2 = ((const float4*)p)[2];
    float4 f3 = ((const float4*)p)[3];
    float ff[16] = {f0.x, f0.y, f0.z, f0.w, f1.x, f1.y, f1.z, f1.w,
                    f2.x, f2.y, f2.z, f2.w, f3.x, f3.y, f3.z, f3.w};
    unsigned hh[8];
#pragma unroll
    for (int e = 0; e < 8; ++e)
        hh[e] = (unsigned)f2bf(ff[2 * e]) | ((unsigned)f2bf(ff[2 * e + 1]) << 16);
    uint4 u0 = {hh[0], hh[1], hh[2], hh[3]};
    uint4 u1 = {hh[4], hh[5], hh[6], hh[7]};
    *(uint4*)&dst[srow][sc0] = u0;
    *(uint4*)&dst[srow][sc0 + 8] = u1;
}

__global__ __launch_bounds__(256, 4) void pass1_kernel(
    const float* __restrict__ x,
    const float* __restrict__ Wk, const float* __restrict__ bk,
    const float* __restrict__ Wv, const float* __restrict__ bv,
    float* __restrict__ kvPart, float* __restrict__ ksPart,
    float* __restrict__ kvFin, float* __restrict__ ksFin)
{
    __shared__ unsigned short kpT[64][72];       // kp transposed [m][n]; startup: W staging
    __shared__ unsigned short vT[64][72];        // v  transposed [d][n]
    __shared__ unsigned short wkF[8][64][8];     // B-frags: [j*2+kk][lane][e]
    __shared__ unsigned short wvF[8][64][8];

    const int tid = threadIdx.x;
    const int w = tid >> 6, l = tid & 63, l15 = l & 15, lg = l >> 4;
    const int srow = tid >> 2, sc0 = (tid & 3) * 16;

    // issue first x-tile loads EARLY: latency hides under W staging below
    const int t0 = blockIdx.x * TPB1;
    const float* xbase = x + ((size_t)t0 * 64 + w * 16 + l15) * 64 + lg * 8;
    float4 c0 = *(const float4*)(xbase + 0);
    float4 c1 = *(const float4*)(xbase + 4);
    float4 c2 = *(const float4*)(xbase + 32);
    float4 c3 = *(const float4*)(xbase + 36);

    // block 0 zero-inits the atomic-reduce targets (ws is poisoned 0xAA)
    if (blockIdx.x == 0) {
        const f32x4 z4 = (f32x4){0.f, 0.f, 0.f, 0.f};
#pragma unroll
        for (int i = 0; i < 4; ++i)
            *(f32x4*)(kvFin + tid * 16 + i * 4) = z4;
        if (tid < 64) ksFin[tid] = 0.f;
    }

    // ---- startup: coalesced W staging -> LDS bf16 -> frag build ----
    {
        const float* Ws[2] = {Wk, Wv};
        unsigned short (*Fs[2])[64][8] = {wkF, wvF};
#pragma unroll
        for (int m = 0; m < 2; ++m) {
            stage_mat(Ws[m], kpT, srow, sc0);
            __syncthreads();
            // wave w builds frag j=w: F[j*2+kk][lane][e] = W[kk*32+lg*8+e][j*16+l15]
#pragma unroll
            for (int kk = 0; kk < 2; ++kk) {
                short8 t;
#pragma unroll
                for (int e = 0; e < 8; ++e)
                    t[e] = (short)kpT[kk * 32 + lg * 8 + e][w * 16 + l15];
                *(short8*)&Fs[m][w * 2 + kk][l][0] = t;
            }
            __syncthreads();
        }
    }
    float bkl[4], bvl[4];
#pragma unroll
    for (int j = 0; j < 4; ++j) { bkl[j] = bk[j * 16 + l15]; bvl[j] = bv[j * 16 + l15]; }

    f32x4 akv[4];
#pragma unroll
    for (int j = 0; j < 4; ++j) akv[j] = (f32x4){0.f, 0.f, 0.f, 0.f};
    float ks[4] = {0.f, 0.f, 0.f, 0.f};

    const int nbase = w * 16 + lg * 4;

    for (int t = 0; t < TPB1; ++t) {
        // prefetch next tile (safe re-read of current on last iter)
        const float* xn = xbase + (size_t)((t + 1 < TPB1) ? (t + 1) : t) * 4096;
        float4 n0 = *(const float4*)(xn + 0);
        float4 n1 = *(const float4*)(xn + 4);
        float4 n2 = *(const float4*)(xn + 32);
        float4 n3 = *(const float4*)(xn + 36);

        short8 a0 = cvt8(c0, c1);
        short8 a1 = cvt8(c2, c3);

#pragma unroll
        for (int j = 0; j < 4; ++j) {
            short8 bk0 = *(const short8*)&wkF[j * 2 + 0][l][0];
            short8 bk1 = *(const short8*)&wkF[j * 2 + 1][l][0];
            short8 bv0 = *(const short8*)&wvF[j * 2 + 0][l][0];
            short8 bv1 = *(const short8*)&wvF[j * 2 + 1][l][0];
            f32x4 z = (f32x4){0.f, 0.f, 0.f, 0.f};
            f32x4 ak = __builtin_amdgcn_mfma_f32_16x16x32_bf16(a0, bk0, z, 0, 0, 0);
            ak = __builtin_amdgcn_mfma_f32_16x16x32_bf16(a1, bk1, ak, 0, 0, 0);
            f32x4 av = __builtin_amdgcn_mfma_f32_16x16x32_bf16(a0, bv0, z, 0, 0, 0);
            av = __builtin_amdgcn_mfma_f32_16x16x32_bf16(a1, bv1, av, 0, 0, 0);
            unsigned short h[4], g[4];
#pragma unroll
            for (int r = 0; r < 4; ++r) {
                float kp = fmaxf(ak[r] + bkl[j], 0.f) + EPS;
                ks[j] += kp;
                h[r] = f2bf(kp);
                g[r] = f2bf(av[r] + bvl[j]);
            }
            uint2 hp = {(unsigned)h[0] | ((unsigned)h[1] << 16), (unsigned)h[2] | ((unsigned)h[3] << 16)};
            uint2 gp = {(unsigned)g[0] | ((unsigned)g[1] << 16), (unsigned)g[2] | ((unsigned)g[3] << 16)};
            *(uint2*)&kpT[j * 16 + l15][nbase] = hp;   // kpT[m][n]
            *(uint2*)&vT[j * 16 + l15][nbase] = gp;    // vT[d][n]
        }
        lds_barrier();
        // kv[m][d] += sum_n kp[n][m] * v[n][d]; wave w owns m in [w*16, w*16+16)
        short8 ka0 = *(const short8*)&kpT[w * 16 + l15][lg * 8];
        short8 ka1 = *(const short8*)&kpT[w * 16 + l15][32 + lg * 8];
#pragma unroll
        for (int j = 0; j < 4; ++j) {
            short8 vb0 = *(const short8*)&vT[j * 16 + l15][lg * 8];
            short8 vb1 = *(const short8*)&vT[j * 16 + l15][32 + lg * 8];
            akv[j] = __builtin_amdgcn_mfma_f32_16x16x32_bf16(ka0, vb0, akv[j], 0, 0, 0);
            akv[j] = __builtin_amdgcn_mfma_f32_16x16x32_bf16(ka1, vb1, akv[j], 0, 0, 0);
        }
        lds_barrier();
        c0 = n0; c1 = n1; c2 = n2; c3 = n3;
    }

    // per-block partial stores (plain, coalesced)
    float* kvs = kvPart + (size_t)blockIdx.x * 4096;
#pragma unroll
    for (int j = 0; j < 4; ++j)
#pragma unroll
        for (int r = 0; r < 4; ++r)
            kvs[(size_t)(w * 16 + lg * 4 + r) * 64 + j * 16 + l15] = akv[j][r];
#pragma unroll
    for (int j = 0; j < 4; ++j) {
        float s = ks[j];
        s += __shfl_xor(s, 16, 64);
        s += __shfl_xor(s, 32, 64);
        if (lg == 0) ksPart[(size_t)blockIdx.x * 256 + w * 64 + j * 16 + l15] = s;
    }
}

// 20 blocks: b<16 -> sum kvPart rows b*32..b*32+31 (coalesced) -> atomicAdd
//            into kvFin; b>=16 -> sum ksPart rows (b-16)*128..+127 -> ksFin
__global__ __launch_bounds__(256, 4) void reduce_kernel(
    const float* __restrict__ kvPart, const float* __restrict__ ksPart,
    float* __restrict__ kvFin, float* __restrict__ ksFin)
{
    const int b = blockIdx.x, t = threadIdx.x;
    if (b < 16) {
        f32x4 acc[4];
#pragma unroll
        for (int si = 0; si < 4; ++si) acc[si] = (f32x4){0.f, 0.f, 0.f, 0.f};
        const float* base = kvPart + (size_t)b * 32 * 4096;
#pragma unroll 4
        for (int r = 0; r < 32; ++r)
#pragma unroll
            for (int si = 0; si < 4; ++si)
                acc[si] += *(const f32x4*)(base + (size_t)r * 4096 + si * 1024 + t * 4);
#pragma unroll
        for (int si = 0; si < 4; ++si)
#pragma unroll
            for (int e = 0; e < 4; ++e)
                unsafeAtomicAdd(&kvFin[si * 1024 + t * 4 + e], acc[si][e]);
    } else {
        const int i = b - 16;
        float acc = 0.f;
        const float* p = ksPart + (size_t)i * 128 * 256 + t;
#pragma unroll 8
        for (int r = 0; r < 128; ++r) acc += p[(size_t)r * 256];
        unsafeAtomicAdd(&ksFin[t & 63], acc);
    }
}

__global__ __launch_bounds__(256, 2) void pass2_kernel(
    const float* __restrict__ x, const float* __restrict__ Wq, const float* __restrict__ bq,
    const float* __restrict__ kvFin, const float* __restrict__ ksFin,
    float* __restrict__ out)
{
    __shared__ unsigned short stageS[64][72];   // startup staging (Wq, then kv)
    __shared__ unsigned short wqF[8][64][8];    // Wq frags (A-role in swapped proj)

    const int tid = threadIdx.x;
    const int w = tid >> 6, l = tid & 63, l15 = l & 15, lg = l >> 4;
    const int srow = tid >> 2, sc0 = (tid & 3) * 16;

    // issue first x-tile loads EARLY: latency hides under Wq/kv staging below
    const int t0 = blockIdx.x * TPB2;
    const float* xbase = x + ((size_t)t0 * 64 + w * 16 + l15) * 64 + lg * 8;
    float4 c0 = *(const float4*)(xbase + 0);
    float4 c1 = *(const float4*)(xbase + 4);
    float4 c2 = *(const float4*)(xbase + 32);
    float4 c3 = *(const float4*)(xbase + 36);

    stage_mat(Wq, stageS, srow, sc0);
    __syncthreads();
    {
#pragma unroll
        for (int kk = 0; kk < 2; ++kk) {
            short8 t;
#pragma unroll
            for (int e = 0; e < 8; ++e)
                t[e] = (short)stageS[kk * 32 + lg * 8 + e][w * 16 + l15];
            *(short8*)&wqF[w * 2 + kk][l][0] = t;
        }
    }
    __syncthreads();
    stage_mat(kvFin, stageS, srow, sc0);
    __syncthreads();
    // kv A'-frags with permuted contraction pi(lg,e,kk) = (kk*2+(e>>2))*16 + lg*4 + (e&3)
    short8 kvA[4][2];
#pragma unroll
    for (int dj = 0; dj < 4; ++dj)
#pragma unroll
        for (int kk = 0; kk < 2; ++kk) {
            short8 t;
#pragma unroll
            for (int e = 0; e < 8; ++e) {
                int m = (kk * 2 + (e >> 2)) * 16 + lg * 4 + (e & 3);
                t[e] = (short)stageS[m][dj * 16 + l15];
            }
            kvA[dj][kk] = t;
        }
    // per-lane bias / ksum for m = jm*16 + lg*4 + r
    float bql2[4][4], ksl2[4][4];
#pragma unroll
    for (int jm = 0; jm < 4; ++jm)
#pragma unroll
        for (int r = 0; r < 4; ++r) {
            bql2[jm][r] = bq[jm * 16 + lg * 4 + r];
            ksl2[jm][r] = ksFin[jm * 16 + lg * 4 + r];
        }

#pragma unroll
    for (int t = 0; t < TPB2; ++t) {
        const float* xn = xbase + (size_t)((t + 1 < TPB2) ? (t + 1) : t) * 4096;
        float4 n0 = *(const float4*)(xn + 0);
        float4 n1 = *(const float4*)(xn + 4);
        float4 n2 = *(const float4*)(xn + 32);
        float4 n3 = *(const float4*)(xn + 36);

        short8 a0 = cvt8(c0, c1);
        short8 a1 = cvt8(c2, c3);

        // swapped Q projection: lane holds qp[n=w*16+l15][m=jm*16+lg*4+r]
        const f32x4 z = (f32x4){0.f, 0.f, 0.f, 0.f};
        float dp = 0.f;
        short8 qb0, qb1;
#pragma unroll
        for (int jm = 0; jm < 4; ++jm) {
            short8 wq0 = *(const short8*)&wqF[jm * 2 + 0][l][0];
            short8 wq1 = *(const short8*)&wqF[jm * 2 + 1][l][0];
            f32x4 aq = __builtin_amdgcn_mfma_f32_16x16x32_bf16(wq0, a0, z, 0, 0, 0);
            aq = __builtin_amdgcn_mfma_f32_16x16x32_bf16(wq1, a1, aq, 0, 0, 0);
#pragma unroll
            for (int r = 0; r < 4; ++r) {
                float qv = fmaxf(aq[r] + bql2[jm][r], 0.f) + EPS;
                dp += qv * ksl2[jm][r];
                unsigned short h = f2bf(qv);
                if (jm < 2) qb0[(jm & 1) * 4 + r] = (short)h;
                else        qb1[(jm & 1) * 4 + r] = (short)h;
            }
        }
        dp += __shfl_xor(dp, 16, 64);
        dp += __shfl_xor(dp, 32, 64);
        const float inv = __builtin_amdgcn_rcpf(dp);

        const size_t nrow = (size_t)(t0 + t) * 64 + w * 16 + l15;
#pragma unroll
        for (int dj = 0; dj < 4; ++dj) {
            f32x4 nm = __builtin_amdgcn_mfma_f32_16x16x32_bf16(kvA[dj][0], qb0, z, 0, 0, 0);
            nm = __builtin_amdgcn_mfma_f32_16x16x32_bf16(kvA[dj][1], qb1, nm, 0, 0, 0);
            f32x4 o4 = {nm[0] * inv, nm[1] * inv, nm[2] * inv, nm[3] * inv};
            *(f32x4*)(out + nrow * 64 + dj * 16 + lg * 4) = o4;
        }
        c0 = n0; c1 = n1; c2 = n2; c3 = n3;
    }
}

extern "C" void kernel_launch(void* const* d_in, const int* in_sizes, int n_in,
                              void* d_out, int out_size, void* d_ws, size_t ws_size,
                              hipStream_t stream)
{
    const float* x  = (const float*)d_in[0];
    const float* Wq = (const float*)d_in[1];
    const float* bq = (const float*)d_in[2];
    const float* Wk = (const float*)d_in[3];
    const float* bk = (const float*)d_in[4];
    const float* Wv = (const float*)d_in[5];
    const float* bv = (const float*)d_in[6];
    float* out = (float*)d_out;

    float* kvPart = (float*)d_ws;                              // [512][4096] f32
    float* ksPart = kvPart + (size_t)GRID1 * 4096;             // [512][256] f32
    float* kvFin  = ksPart + (size_t)GRID1 * 256;              // [4096] f32
    float* ksFin  = kvFin + 4096;                              // [64] f32

    hipLaunchKernelGGL(pass1_kernel, dim3(GRID1), dim3(256), 0, stream,
                       x, Wk, bk, Wv, bv, kvPart, ksPart, kvFin, ksFin);
    hipLaunchKernelGGL(reduce_kernel, dim3(20), dim3(256), 0, stream,
                       kvPart, ksPart, kvFin, ksFin);
    hipLaunchKernelGGL(pass2_kernel, dim3(GRID2), dim3(256), 0, stream,
                       x, Wq, bq, kvFin, ksFin, out);
}

// Round 18
// 53.641 us; speedup vs baseline: 1.0598x; 1.0598x over previous
//
#include <hip/hip_runtime.h>
#include <hip/hip_bf16.h>

// FAVOR+ bidirectional linear attention, N=262144, D=64, fp32 in/out.
// FINAL (R16 champion, 53.9us): 3-launch latency-distributed pipeline.
// Pass 1 (512 blocks, (256,4)): K/V projections (bf16 MFMA) -> kv via
//   LDS-transpose MFMA accumulate -> per-block partial kv/ksum; block 0
//   zero-inits kvFin/ksFin; first x-tile loads hoisted above staging.
// Reduce (20 blocks): coalesced slice sums -> atomicAdd into kvFin/ksFin.
// Pass 2 (512 blocks, (256,2), zero LDS/barriers in loop): swapped Q-proj
//   qp^T = mfma(Wq, x); out^T = mfma(kvA_pi, qp_repack); denom = per-lane
//   dot + 2 shfl_xor; float4 stores; x loads hoisted above staging.

#define NPTS 262144
#define TILES (NPTS / 64)      // 4096
#define GRID1 512
#define TPB1 (TILES / GRID1)   // 8
#define GRID2 512
#define TPB2 (TILES / GRID2)   // 8
#define EPS 1e-3f

typedef __attribute__((ext_vector_type(8))) short short8;   // 8 x bf16 (4 VGPRs)
typedef __attribute__((ext_vector_type(4))) float f32x4;

__device__ __forceinline__ unsigned short f2bf(float f) {
    unsigned u = __builtin_bit_cast(unsigned, f);
    u += 0x7FFFu + ((u >> 16) & 1u);           // round-to-nearest-even
    return (unsigned short)(u >> 16);
}

__device__ __forceinline__ short8 cvt8(float4 p0, float4 p1) {
    short8 a;
    a[0] = (short)f2bf(p0.x); a[1] = (short)f2bf(p0.y); a[2] = (short)f2bf(p0.z); a[3] = (short)f2bf(p0.w);
    a[4] = (short)f2bf(p1.x); a[5] = (short)f2bf(p1.y); a[6] = (short)f2bf(p1.z); a[7] = (short)f2bf(p1.w);
    return a;
}

// barrier that drains LDS ops only (keeps global prefetch loads in flight)
__device__ __forceinline__ void lds_barrier() {
    asm volatile("s_waitcnt lgkmcnt(0)" ::: "memory");
    __builtin_amdgcn_s_barrier();
}

// coalesced stage of a 64x64 f32 matrix -> LDS bf16 [64][72]
__device__ __forceinline__ void stage_mat(const float* __restrict__ W,
                                          unsigned short (*dst)[72], int srow, int sc0) {
    const float* p = W + srow * 64 + sc0;
    float4 f0 = ((const float4*)p)[0];
    float4 f1 = ((const float4*)p)[1];
    float4 f2 = ((const float4*)p)[2];
    float4 f3 = ((const float4*)p)[3];
    float ff[16] = {f0.x, f0.y, f0.z, f0.w, f1.x, f1.y, f1.z, f1.w,
                    f2.x, f2.y, f2.z, f2.w, f3.x, f3.y, f3.z, f3.w};
    unsigned hh[8];
#pragma unroll
    for (int e = 0; e < 8; ++e)
        hh[e] = (unsigned)f2bf(ff[2 * e]) | ((unsigned)f2bf(ff[2 * e + 1]) << 16);
    uint4 u0 = {hh[0], hh[1], hh[2], hh[3]};
    uint4 u1 = {hh[4], hh[5], hh[6], hh[7]};
    *(uint4*)&dst[srow][sc0] = u0;
    *(uint4*)&dst[srow][sc0 + 8] = u1;
}

__global__ __launch_bounds__(256, 4) void pass1_kernel(
    const float* __restrict__ x,
    const float* __restrict__ Wk, const float* __restrict__ bk,
    const float* __restrict__ Wv, const float* __restrict__ bv,
    float* __restrict__ kvPart, float* __restrict__ ksPart,
    float* __restrict__ kvFin, float* __restrict__ ksFin)
{
    __shared__ unsigned short kpT[64][72];       // kp transposed [m][n]; startup: W staging
    __shared__ unsigned short vT[64][72];        // v  transposed [d][n]
    __shared__ unsigned short wkF[8][64][8];     // B-frags: [j*2+kk][lane][e]
    __shared__ unsigned short wvF[8][64][8];

    const int tid = threadIdx.x;
    const int w = tid >> 6, l = tid & 63, l15 = l & 15, lg = l >> 4;
    const int srow = tid >> 2, sc0 = (tid & 3) * 16;

    // issue first x-tile loads EARLY: latency hides under W staging below
    const int t0 = blockIdx.x * TPB1;
    const float* xbase = x + ((size_t)t0 * 64 + w * 16 + l15) * 64 + lg * 8;
    float4 c0 = *(const float4*)(xbase + 0);
    float4 c1 = *(const float4*)(xbase + 4);
    float4 c2 = *(const float4*)(xbase + 32);
    float4 c3 = *(const float4*)(xbase + 36);

    // block 0 zero-inits the atomic-reduce targets (ws is poisoned 0xAA)
    if (blockIdx.x == 0) {
        const f32x4 z4 = (f32x4){0.f, 0.f, 0.f, 0.f};
#pragma unroll
        for (int i = 0; i < 4; ++i)
            *(f32x4*)(kvFin + tid * 16 + i * 4) = z4;
        if (tid < 64) ksFin[tid] = 0.f;
    }

    // ---- startup: coalesced W staging -> LDS bf16 -> frag build ----
    {
        const float* Ws[2] = {Wk, Wv};
        unsigned short (*Fs[2])[64][8] = {wkF, wvF};
#pragma unroll
        for (int m = 0; m < 2; ++m) {
            stage_mat(Ws[m], kpT, srow, sc0);
            __syncthreads();
            // wave w builds frag j=w: F[j*2+kk][lane][e] = W[kk*32+lg*8+e][j*16+l15]
#pragma unroll
            for (int kk = 0; kk < 2; ++kk) {
                short8 t;
#pragma unroll
                for (int e = 0; e < 8; ++e)
                    t[e] = (short)kpT[kk * 32 + lg * 8 + e][w * 16 + l15];
                *(short8*)&Fs[m][w * 2 + kk][l][0] = t;
            }
            __syncthreads();
        }
    }
    float bkl[4], bvl[4];
#pragma unroll
    for (int j = 0; j < 4; ++j) { bkl[j] = bk[j * 16 + l15]; bvl[j] = bv[j * 16 + l15]; }

    f32x4 akv[4];
#pragma unroll
    for (int j = 0; j < 4; ++j) akv[j] = (f32x4){0.f, 0.f, 0.f, 0.f};
    float ks[4] = {0.f, 0.f, 0.f, 0.f};

    const int nbase = w * 16 + lg * 4;

    for (int t = 0; t < TPB1; ++t) {
        // prefetch next tile (safe re-read of current on last iter)
        const float* xn = xbase + (size_t)((t + 1 < TPB1) ? (t + 1) : t) * 4096;
        float4 n0 = *(const float4*)(xn + 0);
        float4 n1 = *(const float4*)(xn + 4);
        float4 n2 = *(const float4*)(xn + 32);
        float4 n3 = *(const float4*)(xn + 36);

        short8 a0 = cvt8(c0, c1);
        short8 a1 = cvt8(c2, c3);

#pragma unroll
        for (int j = 0; j < 4; ++j) {
            short8 bk0 = *(const short8*)&wkF[j * 2 + 0][l][0];
            short8 bk1 = *(const short8*)&wkF[j * 2 + 1][l][0];
            short8 bv0 = *(const short8*)&wvF[j * 2 + 0][l][0];
            short8 bv1 = *(const short8*)&wvF[j * 2 + 1][l][0];
            f32x4 z = (f32x4){0.f, 0.f, 0.f, 0.f};
            f32x4 ak = __builtin_amdgcn_mfma_f32_16x16x32_bf16(a0, bk0, z, 0, 0, 0);
            ak = __builtin_amdgcn_mfma_f32_16x16x32_bf16(a1, bk1, ak, 0, 0, 0);
            f32x4 av = __builtin_amdgcn_mfma_f32_16x16x32_bf16(a0, bv0, z, 0, 0, 0);
            av = __builtin_amdgcn_mfma_f32_16x16x32_bf16(a1, bv1, av, 0, 0, 0);
            unsigned short h[4], g[4];
#pragma unroll
            for (int r = 0; r < 4; ++r) {
                float kp = fmaxf(ak[r] + bkl[j], 0.f) + EPS;
                ks[j] += kp;
                h[r] = f2bf(kp);
                g[r] = f2bf(av[r] + bvl[j]);
            }
            uint2 hp = {(unsigned)h[0] | ((unsigned)h[1] << 16), (unsigned)h[2] | ((unsigned)h[3] << 16)};
            uint2 gp = {(unsigned)g[0] | ((unsigned)g[1] << 16), (unsigned)g[2] | ((unsigned)g[3] << 16)};
            *(uint2*)&kpT[j * 16 + l15][nbase] = hp;   // kpT[m][n]
            *(uint2*)&vT[j * 16 + l15][nbase] = gp;    // vT[d][n]
        }
        lds_barrier();
        // kv[m][d] += sum_n kp[n][m] * v[n][d]; wave w owns m in [w*16, w*16+16)
        short8 ka0 = *(const short8*)&kpT[w * 16 + l15][lg * 8];
        short8 ka1 = *(const short8*)&kpT[w * 16 + l15][32 + lg * 8];
#pragma unroll
        for (int j = 0; j < 4; ++j) {
            short8 vb0 = *(const short8*)&vT[j * 16 + l15][lg * 8];
            short8 vb1 = *(const short8*)&vT[j * 16 + l15][32 + lg * 8];
            akv[j] = __builtin_amdgcn_mfma_f32_16x16x32_bf16(ka0, vb0, akv[j], 0, 0, 0);
            akv[j] = __builtin_amdgcn_mfma_f32_16x16x32_bf16(ka1, vb1, akv[j], 0, 0, 0);
        }
        lds_barrier();
        c0 = n0; c1 = n1; c2 = n2; c3 = n3;
    }

    // per-block partial stores (plain, coalesced)
    float* kvs = kvPart + (size_t)blockIdx.x * 4096;
#pragma unroll
    for (int j = 0; j < 4; ++j)
#pragma unroll
        for (int r = 0; r < 4; ++r)
            kvs[(size_t)(w * 16 + lg * 4 + r) * 64 + j * 16 + l15] = akv[j][r];
#pragma unroll
    for (int j = 0; j < 4; ++j) {
        float s = ks[j];
        s += __shfl_xor(s, 16, 64);
        s += __shfl_xor(s, 32, 64);
        if (lg == 0) ksPart[(size_t)blockIdx.x * 256 + w * 64 + j * 16 + l15] = s;
    }
}

// 20 blocks: b<16 -> sum kvPart rows b*32..b*32+31 (coalesced) -> atomicAdd
//            into kvFin; b>=16 -> sum ksPart rows (b-16)*128..+127 -> ksFin
__global__ __launch_bounds__(256, 4) void reduce_kernel(
    const float* __restrict__ kvPart, const float* __restrict__ ksPart,
    float* __restrict__ kvFin, float* __restrict__ ksFin)
{
    const int b = blockIdx.x, t = threadIdx.x;
    if (b < 16) {
        f32x4 acc[4];
#pragma unroll
        for (int si = 0; si < 4; ++si) acc[si] = (f32x4){0.f, 0.f, 0.f, 0.f};
        const float* base = kvPart + (size_t)b * 32 * 4096;
#pragma unroll 4
        for (int r = 0; r < 32; ++r)
#pragma unroll
            for (int si = 0; si < 4; ++si)
                acc[si] += *(const f32x4*)(base + (size_t)r * 4096 + si * 1024 + t * 4);
#pragma unroll
        for (int si = 0; si < 4; ++si)
#pragma unroll
            for (int e = 0; e < 4; ++e)
                unsafeAtomicAdd(&kvFin[si * 1024 + t * 4 + e], acc[si][e]);
    } else {
        const int i = b - 16;
        float acc = 0.f;
        const float* p = ksPart + (size_t)i * 128 * 256 + t;
#pragma unroll 8
        for (int r = 0; r < 128; ++r) acc += p[(size_t)r * 256];
        unsafeAtomicAdd(&ksFin[t & 63], acc);
    }
}

__global__ __launch_bounds__(256, 2) void pass2_kernel(
    const float* __restrict__ x, const float* __restrict__ Wq, const float* __restrict__ bq,
    const float* __restrict__ kvFin, const float* __restrict__ ksFin,
    float* __restrict__ out)
{
    __shared__ unsigned short stageS[64][72];   // startup staging (Wq, then kv)
    __shared__ unsigned short wqF[8][64][8];    // Wq frags (A-role in swapped proj)

    const int tid = threadIdx.x;
    const int w = tid >> 6, l = tid & 63, l15 = l & 15, lg = l >> 4;
    const int srow = tid >> 2, sc0 = (tid & 3) * 16;

    // issue first x-tile loads EARLY: latency hides under Wq/kv staging below
    const int t0 = blockIdx.x * TPB2;
    const float* xbase = x + ((size_t)t0 * 64 + w * 16 + l15) * 64 + lg * 8;
    float4 c0 = *(const float4*)(xbase + 0);
    float4 c1 = *(const float4*)(xbase + 4);
    float4 c2 = *(const float4*)(xbase + 32);
    float4 c3 = *(const float4*)(xbase + 36);

    stage_mat(Wq, stageS, srow, sc0);
    __syncthreads();
    {
#pragma unroll
        for (int kk = 0; kk < 2; ++kk) {
            short8 t;
#pragma unroll
            for (int e = 0; e < 8; ++e)
                t[e] = (short)stageS[kk * 32 + lg * 8 + e][w * 16 + l15];
            *(short8*)&wqF[w * 2 + kk][l][0] = t;
        }
    }
    __syncthreads();
    stage_mat(kvFin, stageS, srow, sc0);
    __syncthreads();
    // kv A'-frags with permuted contraction pi(lg,e,kk) = (kk*2+(e>>2))*16 + lg*4 + (e&3)
    short8 kvA[4][2];
#pragma unroll
    for (int dj = 0; dj < 4; ++dj)
#pragma unroll
        for (int kk = 0; kk < 2; ++kk) {
            short8 t;
#pragma unroll
            for (int e = 0; e < 8; ++e) {
                int m = (kk * 2 + (e >> 2)) * 16 + lg * 4 + (e & 3);
                t[e] = (short)stageS[m][dj * 16 + l15];
            }
            kvA[dj][kk] = t;
        }
    // per-lane bias / ksum for m = jm*16 + lg*4 + r
    float bql2[4][4], ksl2[4][4];
#pragma unroll
    for (int jm = 0; jm < 4; ++jm)
#pragma unroll
        for (int r = 0; r < 4; ++r) {
            bql2[jm][r] = bq[jm * 16 + lg * 4 + r];
            ksl2[jm][r] = ksFin[jm * 16 + lg * 4 + r];
        }

    for (int t = 0; t < TPB2; ++t) {
        const float* xn = xbase + (size_t)((t + 1 < TPB2) ? (t + 1) : t) * 4096;
        float4 n0 = *(const float4*)(xn + 0);
        float4 n1 = *(const float4*)(xn + 4);
        float4 n2 = *(const float4*)(xn + 32);
        float4 n3 = *(const float4*)(xn + 36);

        short8 a0 = cvt8(c0, c1);
        short8 a1 = cvt8(c2, c3);

        // swapped Q projection: lane holds qp[n=w*16+l15][m=jm*16+lg*4+r]
        const f32x4 z = (f32x4){0.f, 0.f, 0.f, 0.f};
        float dp = 0.f;
        short8 qb0, qb1;
#pragma unroll
        for (int jm = 0; jm < 4; ++jm) {
            short8 wq0 = *(const short8*)&wqF[jm * 2 + 0][l][0];
            short8 wq1 = *(const short8*)&wqF[jm * 2 + 1][l][0];
            f32x4 aq = __builtin_amdgcn_mfma_f32_16x16x32_bf16(wq0, a0, z, 0, 0, 0);
            aq = __builtin_amdgcn_mfma_f32_16x16x32_bf16(wq1, a1, aq, 0, 0, 0);
#pragma unroll
            for (int r = 0; r < 4; ++r) {
                float qv = fmaxf(aq[r] + bql2[jm][r], 0.f) + EPS;
                dp += qv * ksl2[jm][r];
                unsigned short h = f2bf(qv);
                if (jm < 2) qb0[(jm & 1) * 4 + r] = (short)h;
                else        qb1[(jm & 1) * 4 + r] = (short)h;
            }
        }
        dp += __shfl_xor(dp, 16, 64);
        dp += __shfl_xor(dp, 32, 64);
        const float inv = __builtin_amdgcn_rcpf(dp);

        const size_t nrow = (size_t)(t0 + t) * 64 + w * 16 + l15;
#pragma unroll
        for (int dj = 0; dj < 4; ++dj) {
            f32x4 nm = __builtin_amdgcn_mfma_f32_16x16x32_bf16(kvA[dj][0], qb0, z, 0, 0, 0);
            nm = __builtin_amdgcn_mfma_f32_16x16x32_bf16(kvA[dj][1], qb1, nm, 0, 0, 0);
            f32x4 o4 = {nm[0] * inv, nm[1] * inv, nm[2] * inv, nm[3] * inv};
            *(f32x4*)(out + nrow * 64 + dj * 16 + lg * 4) = o4;
        }
        c0 = n0; c1 = n1; c2 = n2; c3 = n3;
    }
}

extern "C" void kernel_launch(void* const* d_in, const int* in_sizes, int n_in,
                              void* d_out, int out_size, void* d_ws, size_t ws_size,
                              hipStream_t stream)
{
    const float* x  = (const float*)d_in[0];
    const float* Wq = (const float*)d_in[1];
    const float* bq = (const float*)d_in[2];
    const float* Wk = (const float*)d_in[3];
    const float* bk = (const float*)d_in[4];
    const float* Wv = (const float*)d_in[5];
    const float* bv = (const float*)d_in[6];
    float* out = (float*)d_out;

    float* kvPart = (float*)d_ws;                              // [512][4096] f32
    float* ksPart = kvPart + (size_t)GRID1 * 4096;             // [512][256] f32
    float* kvFin  = ksPart + (size_t)GRID1 * 256;              // [4096] f32
    float* ksFin  = kvFin + 4096;                              // [64] f32

    hipLaunchKernelGGL(pass1_kernel, dim3(GRID1), dim3(256), 0, stream,
                       x, Wk, bk, Wv, bv, kvPart, ksPart, kvFin, ksFin);
    hipLaunchKernelGGL(reduce_kernel, dim3(20), dim3(256), 0, stream,
                       kvPart, ksPart, kvFin, ksFin);
    hipLaunchKernelGGL(pass2_kernel, dim3(GRID2), dim3(256), 0, stream,
                       x, Wq, bq, kvFin, ksFin, out);
}